// Round 1
// baseline (1101.746 us; speedup 1.0000x reference)
//
#include <hip/hip_runtime.h>
#include <hip/hip_bf16.h>

#define TT 512
#define NCH 10

__device__ __forceinline__ float fast_tanh(float v) {
    // tanh(x) = 1 - 2/(exp(2x)+1); correct limits for |x| large
    float e = __expf(2.0f * v);
    return 1.0f - 2.0f / (e + 1.0f);
}

// One block per batch row: conv1->relu, conv2->relu, conv3->tanh, VQ(softmax), d1->relu, d2->relu
// Writes flat (B, 5120) f32 to workspace.
__global__ __launch_bounds__(256, 2) void enc_dec_kernel(
    const float* __restrict__ x,
    const float* __restrict__ w1, const float* __restrict__ b1,
    const float* __restrict__ w2, const float* __restrict__ b2,
    const float* __restrict__ w3, const float* __restrict__ b3,
    const float* __restrict__ code,
    const float* __restrict__ d1w, const float* __restrict__ d1b,
    const float* __restrict__ d2w, const float* __restrict__ d2b,
    float* __restrict__ flat)
{
    __shared__ float sw1[5*3], sb1[5];
    __shared__ float sw2[10*5*5], sb2[10];
    __shared__ float sw3[10*10*7], sb3[10];
    __shared__ float scode[10*32], sc2[32];
    __shared__ float sd1w[10*10*5], sd1b[10];
    __shared__ float sd2w[10*10*5], sd2b[10];
    __shared__ float xrow[TT];
    __shared__ float bufA[NCH*TT];
    __shared__ float bufB[NCH*TT];

    const int tid = threadIdx.x;
    const int b = blockIdx.x;

    // ---- cooperative parameter loads ----
    for (int i = tid; i < 5*3;    i += 256) sw1[i] = w1[i];
    for (int i = tid; i < 10*5*5; i += 256) sw2[i] = w2[i];
    for (int i = tid; i < 10*10*7;i += 256) sw3[i] = w3[i];
    for (int i = tid; i < 10*32;  i += 256) scode[i] = code[i];
    for (int i = tid; i < 10*10*5;i += 256) { sd1w[i] = d1w[i]; sd2w[i] = d2w[i]; }
    if (tid < 10) {
        if (tid < 5) sb1[tid] = b1[tid];
        sb2[tid] = b2[tid];
        sb3[tid] = b3[tid];
        sd1b[tid] = d1b[tid];
        sd2b[tid] = d2b[tid];
    }
    for (int i = tid; i < TT; i += 256) xrow[i] = x[(size_t)b*TT + i];
    __syncthreads();
    if (tid < 32) {
        float s = 0.f;
        #pragma unroll
        for (int c = 0; c < 10; ++c) { float v = scode[c*32+tid]; s = fmaf(v, v, s); }
        sc2[tid] = s;
    }
    __syncthreads();

    // ---- conv1: 1ch -> 5ch, k=3, pad=1, relu   (xrow -> bufA[0..4]) ----
    for (int t = tid; t < TT; t += 256) {
        float xm = (t > 0)    ? xrow[t-1] : 0.f;
        float x0 = xrow[t];
        float xp = (t < TT-1) ? xrow[t+1] : 0.f;
        #pragma unroll
        for (int o = 0; o < 5; ++o) {
            float a = fmaf(sw1[o*3+0], xm, fmaf(sw1[o*3+1], x0, fmaf(sw1[o*3+2], xp, sb1[o])));
            bufA[o*TT + t] = fmaxf(a, 0.f);
        }
    }
    __syncthreads();

    // ---- conv2: 5ch -> 10ch, k=5, pad=2, relu  (bufA -> bufB) ----
    for (int t = tid; t < TT; t += 256) {
        float in[5][5];
        #pragma unroll
        for (int i = 0; i < 5; ++i)
            #pragma unroll
            for (int j = 0; j < 5; ++j) {
                int tt = t - 2 + j;
                in[i][j] = (tt >= 0 && tt < TT) ? bufA[i*TT + tt] : 0.f;
            }
        #pragma unroll
        for (int o = 0; o < 10; ++o) {
            float a = sb2[o];
            #pragma unroll
            for (int i = 0; i < 5; ++i)
                #pragma unroll
                for (int j = 0; j < 5; ++j)
                    a = fmaf(sw2[(o*5+i)*5+j], in[i][j], a);
            bufB[o*TT + t] = fmaxf(a, 0.f);
        }
    }
    __syncthreads();

    // ---- conv3: 10ch -> 10ch, k=7, pad=3, tanh (bufB -> bufA) ----
    for (int t = tid; t < TT; t += 256) {
        float acc[10];
        #pragma unroll
        for (int o = 0; o < 10; ++o) acc[o] = sb3[o];
        #pragma unroll
        for (int i = 0; i < 10; ++i) {
            float tap[7];
            #pragma unroll
            for (int j = 0; j < 7; ++j) {
                int tt = t - 3 + j;
                tap[j] = (tt >= 0 && tt < TT) ? bufB[i*TT + tt] : 0.f;
            }
            #pragma unroll
            for (int o = 0; o < 10; ++o) {
                #pragma unroll
                for (int j = 0; j < 7; ++j)
                    acc[o] = fmaf(sw3[(o*10+i)*7+j], tap[j], acc[o]);
            }
        }
        #pragma unroll
        for (int o = 0; o < 10; ++o) bufA[o*TT + t] = fast_tanh(acc[o]);
    }
    __syncthreads();

    // ---- VQ: softmax(-dist) over 32 codes; x2 term drops (shift-invariance) ----
    // s[k] = 2*<h,code_k> - |code_k|^2 ; prob = softmax(s); q = prob @ code^T
    for (int t = tid; t < TT; t += 256) {
        float hv[10];
        #pragma unroll
        for (int c = 0; c < 10; ++c) hv[c] = bufA[c*TT + t];
        float s[32];
        float m = -1e30f;
        #pragma unroll
        for (int k = 0; k < 32; ++k) {
            float cr = 0.f;
            #pragma unroll
            for (int c = 0; c < 10; ++c) cr = fmaf(hv[c], scode[c*32+k], cr);
            float v = fmaf(2.f, cr, -sc2[k]);
            s[k] = v;
            m = fmaxf(m, v);
        }
        float sum = 0.f;
        #pragma unroll
        for (int k = 0; k < 32; ++k) { s[k] = __expf(s[k] - m); sum += s[k]; }
        float inv = 1.0f / sum;
        #pragma unroll
        for (int c = 0; c < 10; ++c) {
            float qv = 0.f;
            #pragma unroll
            for (int k = 0; k < 32; ++k) qv = fmaf(s[k], scode[c*32+k], qv);
            bufB[c*TT + t] = qv * inv;
        }
    }
    __syncthreads();

    // ---- d1: 10ch -> 10ch, k=5, pad=2, relu (bufB -> bufA) ----
    for (int t = tid; t < TT; t += 256) {
        float acc[10];
        #pragma unroll
        for (int o = 0; o < 10; ++o) acc[o] = sd1b[o];
        #pragma unroll
        for (int i = 0; i < 10; ++i) {
            float tap[5];
            #pragma unroll
            for (int j = 0; j < 5; ++j) {
                int tt = t - 2 + j;
                tap[j] = (tt >= 0 && tt < TT) ? bufB[i*TT + tt] : 0.f;
            }
            #pragma unroll
            for (int o = 0; o < 10; ++o) {
                #pragma unroll
                for (int j = 0; j < 5; ++j)
                    acc[o] = fmaf(sd1w[(o*10+i)*5+j], tap[j], acc[o]);
            }
        }
        #pragma unroll
        for (int o = 0; o < 10; ++o) bufA[o*TT + t] = fmaxf(acc[o], 0.f);
    }
    __syncthreads();

    // ---- d2: 10ch -> 10ch, k=5, pad=2, relu (bufA -> bufB) ----
    for (int t = tid; t < TT; t += 256) {
        float acc[10];
        #pragma unroll
        for (int o = 0; o < 10; ++o) acc[o] = sd2b[o];
        #pragma unroll
        for (int i = 0; i < 10; ++i) {
            float tap[5];
            #pragma unroll
            for (int j = 0; j < 5; ++j) {
                int tt = t - 2 + j;
                tap[j] = (tt >= 0 && tt < TT) ? bufA[i*TT + tt] : 0.f;
            }
            #pragma unroll
            for (int o = 0; o < 10; ++o) {
                #pragma unroll
                for (int j = 0; j < 5; ++j)
                    acc[o] = fmaf(sd2w[(o*10+i)*5+j], tap[j], acc[o]);
            }
        }
        #pragma unroll
        for (int o = 0; o < 10; ++o) bufB[o*TT + t] = fmaxf(acc[o], 0.f);
    }
    __syncthreads();

    // ---- flat row = bufB contiguous (c*512 + t) ----
    for (int i = tid; i < NCH*TT; i += 256) flat[(size_t)b*(NCH*TT) + i] = bufB[i];
}

// FC: out[b][n] = tanh(fcb[n] + dot(flat[b], fcw[n]))  M=1024 N=512 K=5120
// BM=64 BN=32 BK=32, 256 threads, 4m x 2n per thread, register prefetch.
#define BK 32
__global__ __launch_bounds__(256, 2) void fc_kernel(
    const float* __restrict__ A,    // (1024, 5120)
    const float* __restrict__ B,    // (512, 5120)
    const float* __restrict__ bias, // (512)
    float* __restrict__ out)        // (1024, 512)
{
    const int tid = threadIdx.x;
    const int bn = blockIdx.x;  // 16 tiles of 32 cols
    const int bm = blockIdx.y;  // 16 tiles of 64 rows

    __shared__ float As[BK][68];  // [k][m], padded
    __shared__ float Bs[BK][36];  // [k][n], padded

    const float* Ag = A + (size_t)(bm*64)*5120;
    const float* Bg = B + (size_t)(bn*32)*5120;

    const int a_kq = (tid % 8) * 4;    // k offset 0..28
    const int a_m  = tid / 8;          // 0..31 (second half at +32)
    const int m0 = (tid / 16) * 4;
    const int n0 = (tid % 16) * 2;

    float4 pa0 = *(const float4*)&Ag[(size_t)a_m      * 5120 + a_kq];
    float4 pa1 = *(const float4*)&Ag[(size_t)(a_m+32) * 5120 + a_kq];
    float4 pb0 = *(const float4*)&Bg[(size_t)a_m      * 5120 + a_kq];

    float acc[4][2] = {};

    for (int k0 = 0; k0 < 5120; k0 += BK) {
        #pragma unroll
        for (int j = 0; j < 4; ++j) {
            As[a_kq + j][a_m]      = ((const float*)&pa0)[j];
            As[a_kq + j][a_m + 32] = ((const float*)&pa1)[j];
            Bs[a_kq + j][a_m]      = ((const float*)&pb0)[j];
        }
        __syncthreads();
        if (k0 + BK < 5120) {
            pa0 = *(const float4*)&Ag[(size_t)a_m      * 5120 + (k0 + BK) + a_kq];
            pa1 = *(const float4*)&Ag[(size_t)(a_m+32) * 5120 + (k0 + BK) + a_kq];
            pb0 = *(const float4*)&Bg[(size_t)a_m      * 5120 + (k0 + BK) + a_kq];
        }
        #pragma unroll
        for (int k = 0; k < BK; ++k) {
            float4 av = *(const float4*)&As[k][m0];
            float2 bv = *(const float2*)&Bs[k][n0];
            const float* ap = (const float*)&av;
            const float* bp = (const float*)&bv;
            #pragma unroll
            for (int i = 0; i < 4; ++i)
                #pragma unroll
                for (int j = 0; j < 2; ++j)
                    acc[i][j] = fmaf(ap[i], bp[j], acc[i][j]);
        }
        __syncthreads();
    }

    #pragma unroll
    for (int i = 0; i < 4; ++i) {
        int row = bm*64 + m0 + i;
        #pragma unroll
        for (int j = 0; j < 2; ++j) {
            int col = bn*32 + n0 + j;
            out[(size_t)row*512 + col] = fast_tanh(acc[i][j] + bias[col]);
        }
    }
}

extern "C" void kernel_launch(void* const* d_in, const int* in_sizes, int n_in,
                              void* d_out, int out_size, void* d_ws, size_t ws_size,
                              hipStream_t stream) {
    const float* x    = (const float*)d_in[0];
    const float* w1   = (const float*)d_in[1];
    const float* b1   = (const float*)d_in[2];
    const float* w2   = (const float*)d_in[3];
    const float* b2   = (const float*)d_in[4];
    const float* w3   = (const float*)d_in[5];
    const float* b3   = (const float*)d_in[6];
    const float* code = (const float*)d_in[7];
    const float* d1w  = (const float*)d_in[8];
    const float* d1b  = (const float*)d_in[9];
    const float* d2w  = (const float*)d_in[10];
    const float* d2b  = (const float*)d_in[11];
    const float* fcw  = (const float*)d_in[12];
    const float* fcb  = (const float*)d_in[13];
    float* out  = (float*)d_out;
    float* flat = (float*)d_ws;   // (B, 5120) f32 = 20 MB

    const int Bsz = in_sizes[0] / TT;   // 1024

    enc_dec_kernel<<<Bsz, 256, 0, stream>>>(x, w1, b1, w2, b2, w3, b3, code,
                                            d1w, d1b, d2w, d2b, flat);

    dim3 grid(512 / 32, Bsz / 64);      // (16, 16)
    fc_kernel<<<grid, 256, 0, stream>>>(flat, fcw, fcb, out);
}

// Round 2
// 247.251 us; speedup vs baseline: 4.4560x; 4.4560x over previous
//
#include <hip/hip_runtime.h>
#include <hip/hip_bf16.h>

#define TT 512
#define TS 520   // LDS row stride: 4-halo | 512 | 4-halo
#define HO 4
#define NCH 10

__device__ __forceinline__ float rlane(float v, int l) {
    return __uint_as_float(__builtin_amdgcn_readlane(__float_as_uint(v), l));
}
__device__ __forceinline__ float fast_tanh(float v) {
    float e = __expf(2.0f * v);
    return 1.0f - 2.0f / (e + 1.0f);
}

// One block per batch row, 256 threads, each thread owns t0=tid and t1=tid+256.
// Weights live in VGPRs (64 per reg) and are broadcast per-use via v_readlane
// (compile-time lane indices from fully unrolled loops) -> no LDS traffic, no
// per-thread weight arrays, no scratch.
__global__ __launch_bounds__(256, 3) void enc_dec_kernel(
    const float* __restrict__ x,
    const float* __restrict__ w1, const float* __restrict__ b1,
    const float* __restrict__ w2, const float* __restrict__ b2,
    const float* __restrict__ w3, const float* __restrict__ b3,
    const float* __restrict__ code,
    const float* __restrict__ d1w, const float* __restrict__ d1b,
    const float* __restrict__ d2w, const float* __restrict__ d2b,
    float* __restrict__ flat)
{
    __shared__ float xbuf[TS];
    __shared__ float bufA[NCH * TS];
    __shared__ float bufB[NCH * TS];

    const int tid  = threadIdx.x;
    const int lane = tid & 63;
    const int b    = blockIdx.x;
    const int t0   = tid;
    const int t1   = tid + 256;

    // ---- init: zero halos, load x row (vectorized) ----
    if (tid < 80) {                       // 10 ch x 8 halo slots, both buffers
        int c = tid >> 3, j = tid & 7;
        int pos = c * TS + ((j < 4) ? j : TT + j);
        bufA[pos] = 0.f;
        bufB[pos] = 0.f;
    }
    if (tid < 8) xbuf[(tid < 4) ? tid : TT + tid] = 0.f;
    if (tid < 128)
        *(float4*)&xbuf[HO + tid * 4] = ((const float4*)(x + (size_t)b * TT))[tid];
    __syncthreads();

    // ================= conv1: 1ch -> 5ch, k=3, pad=1, relu =================
    {
        float w1r = w1[min(lane, 14)];              // 15 weights
        float b1r = (lane < 5) ? b1[lane] : 0.f;
        float xm0 = xbuf[HO + t0 - 1], x00 = xbuf[HO + t0], xp0 = xbuf[HO + t0 + 1];
        float xm1 = xbuf[HO + t1 - 1], x01 = xbuf[HO + t1], xp1 = xbuf[HO + t1 + 1];
        #pragma unroll
        for (int o = 0; o < 5; ++o) {
            float k0 = rlane(w1r, o * 3 + 0);
            float k1 = rlane(w1r, o * 3 + 1);
            float k2 = rlane(w1r, o * 3 + 2);
            float bb = rlane(b1r, o);
            float a0 = fmaf(k0, xm0, fmaf(k1, x00, fmaf(k2, xp0, bb)));
            float a1 = fmaf(k0, xm1, fmaf(k1, x01, fmaf(k2, xp1, bb)));
            bufA[o * TS + HO + t0] = fmaxf(a0, 0.f);
            bufA[o * TS + HO + t1] = fmaxf(a1, 0.f);
        }
    }
    __syncthreads();

    // ================= conv2: 5ch -> 10ch, k=5, pad=2, relu ================
    {
        float wr[4];
        #pragma unroll
        for (int r = 0; r < 4; ++r) wr[r] = w2[min(r * 64 + lane, 249)];
        float br = (lane < 10) ? b2[lane] : 0.f;
        float a0[10], a1[10];
        #pragma unroll
        for (int o = 0; o < 10; ++o) { float bb = rlane(br, o); a0[o] = bb; a1[o] = bb; }
        #pragma unroll
        for (int i = 0; i < 5; ++i) {
            #pragma unroll
            for (int j = 0; j < 5; ++j) {
                float ta = bufA[i * TS + HO + t0 - 2 + j];
                float tb = bufA[i * TS + HO + t1 - 2 + j];
                #pragma unroll
                for (int o = 0; o < 10; ++o) {
                    const int e = (o * 5 + i) * 5 + j;
                    float wv = rlane(wr[e >> 6], e & 63);
                    a0[o] = fmaf(wv, ta, a0[o]);
                    a1[o] = fmaf(wv, tb, a1[o]);
                }
            }
        }
        #pragma unroll
        for (int o = 0; o < 10; ++o) {
            bufB[o * TS + HO + t0] = fmaxf(a0[o], 0.f);
            bufB[o * TS + HO + t1] = fmaxf(a1[o], 0.f);
        }
    }
    __syncthreads();

    // ================ conv3: 10ch -> 10ch, k=7, pad=3, tanh ================
    {
        float wr[11];
        #pragma unroll
        for (int r = 0; r < 11; ++r) wr[r] = w3[min(r * 64 + lane, 699)];
        float br = (lane < 10) ? b3[lane] : 0.f;
        float a0[10], a1[10];
        #pragma unroll
        for (int o = 0; o < 10; ++o) { float bb = rlane(br, o); a0[o] = bb; a1[o] = bb; }
        #pragma unroll
        for (int i = 0; i < 10; ++i) {
            #pragma unroll
            for (int j = 0; j < 7; ++j) {
                float ta = bufB[i * TS + HO + t0 - 3 + j];
                float tb = bufB[i * TS + HO + t1 - 3 + j];
                #pragma unroll
                for (int o = 0; o < 10; ++o) {
                    const int e = (o * 10 + i) * 7 + j;
                    float wv = rlane(wr[e >> 6], e & 63);
                    a0[o] = fmaf(wv, ta, a0[o]);
                    a1[o] = fmaf(wv, tb, a1[o]);
                }
            }
        }
        #pragma unroll
        for (int o = 0; o < 10; ++o) {
            bufA[o * TS + HO + t0] = fast_tanh(a0[o]);
            bufA[o * TS + HO + t1] = fast_tanh(a1[o]);
        }
    }
    __syncthreads();

    // ====== VQ: softmax(2*cross - c2) over 32 codes; no max pass needed ======
    // |2*cross - c2| <= ~21 -> exp safely finite in f32.
    {
        float cr5[5];
        #pragma unroll
        for (int r = 0; r < 5; ++r) cr5[r] = code[min(r * 64 + lane, 319)];
        float hv0[10], hv1[10];
        #pragma unroll
        for (int c = 0; c < 10; ++c) {
            hv0[c] = bufA[c * TS + HO + t0];
            hv1[c] = bufA[c * TS + HO + t1];
        }
        float qv0[10] = {}, qv1[10] = {};
        float sum0 = 0.f, sum1 = 0.f;
        #pragma unroll
        for (int k = 0; k < 32; ++k) {
            float cvv[10];
            float c0 = 0.f, c1 = 0.f, cc = 0.f;
            #pragma unroll
            for (int c = 0; c < 10; ++c) {
                const int e = c * 32 + k;
                float cv = rlane(cr5[e >> 6], e & 63);
                cvv[c] = cv;
                c0 = fmaf(cv, hv0[c], c0);
                c1 = fmaf(cv, hv1[c], c1);
                cc = fmaf(cv, cv, cc);
            }
            float e0 = __expf(fmaf(2.f, c0, -cc));
            float e1 = __expf(fmaf(2.f, c1, -cc));
            sum0 += e0;
            sum1 += e1;
            #pragma unroll
            for (int c = 0; c < 10; ++c) {
                qv0[c] = fmaf(e0, cvv[c], qv0[c]);
                qv1[c] = fmaf(e1, cvv[c], qv1[c]);
            }
        }
        float inv0 = 1.0f / sum0, inv1 = 1.0f / sum1;
        #pragma unroll
        for (int c = 0; c < 10; ++c) {
            bufB[c * TS + HO + t0] = qv0[c] * inv0;
            bufB[c * TS + HO + t1] = qv1[c] * inv1;
        }
    }
    __syncthreads();

    // ================= d1: 10ch -> 10ch, k=5, pad=2, relu ==================
    {
        float wr[8];
        #pragma unroll
        for (int r = 0; r < 8; ++r) wr[r] = d1w[min(r * 64 + lane, 499)];
        float br = (lane < 10) ? d1b[lane] : 0.f;
        float a0[10], a1[10];
        #pragma unroll
        for (int o = 0; o < 10; ++o) { float bb = rlane(br, o); a0[o] = bb; a1[o] = bb; }
        #pragma unroll
        for (int i = 0; i < 10; ++i) {
            #pragma unroll
            for (int j = 0; j < 5; ++j) {
                float ta = bufB[i * TS + HO + t0 - 2 + j];
                float tb = bufB[i * TS + HO + t1 - 2 + j];
                #pragma unroll
                for (int o = 0; o < 10; ++o) {
                    const int e = (o * 10 + i) * 5 + j;
                    float wv = rlane(wr[e >> 6], e & 63);
                    a0[o] = fmaf(wv, ta, a0[o]);
                    a1[o] = fmaf(wv, tb, a1[o]);
                }
            }
        }
        #pragma unroll
        for (int o = 0; o < 10; ++o) {
            bufA[o * TS + HO + t0] = fmaxf(a0[o], 0.f);
            bufA[o * TS + HO + t1] = fmaxf(a1[o], 0.f);
        }
    }
    __syncthreads();

    // ================= d2: 10ch -> 10ch, k=5, pad=2, relu ==================
    {
        float wr[8];
        #pragma unroll
        for (int r = 0; r < 8; ++r) wr[r] = d2w[min(r * 64 + lane, 499)];
        float br = (lane < 10) ? d2b[lane] : 0.f;
        float a0[10], a1[10];
        #pragma unroll
        for (int o = 0; o < 10; ++o) { float bb = rlane(br, o); a0[o] = bb; a1[o] = bb; }
        #pragma unroll
        for (int i = 0; i < 10; ++i) {
            #pragma unroll
            for (int j = 0; j < 5; ++j) {
                float ta = bufA[i * TS + HO + t0 - 2 + j];
                float tb = bufA[i * TS + HO + t1 - 2 + j];
                #pragma unroll
                for (int o = 0; o < 10; ++o) {
                    const int e = (o * 10 + i) * 5 + j;
                    float wv = rlane(wr[e >> 6], e & 63);
                    a0[o] = fmaf(wv, ta, a0[o]);
                    a1[o] = fmaf(wv, tb, a1[o]);
                }
            }
        }
        #pragma unroll
        for (int o = 0; o < 10; ++o) {
            bufB[o * TS + HO + t0] = fmaxf(a0[o], 0.f);
            bufB[o * TS + HO + t1] = fmaxf(a1[o], 0.f);
        }
    }
    __syncthreads();

    // ---- flat row: (c, t) contiguous, float4 ----
    {
        float* dst = flat + (size_t)b * (NCH * TT);
        for (int i = tid; i < NCH * TT / 4; i += 256) {     // 1280 float4s
            int c  = i >> 7;
            int t4 = (i & 127) << 2;
            *(float4*)&dst[c * TT + t4] = *(const float4*)&bufB[c * TS + HO + t4];
        }
    }
}

// FC: out[b][n] = tanh(fcb[n] + dot(flat[b], fcw[n]))  M=1024 N=512 K=5120
#define BK 32
__global__ __launch_bounds__(256, 2) void fc_kernel(
    const float* __restrict__ A,    // (1024, 5120)
    const float* __restrict__ B,    // (512, 5120)
    const float* __restrict__ bias, // (512)
    float* __restrict__ out)        // (1024, 512)
{
    const int tid = threadIdx.x;
    const int bn = blockIdx.x;
    const int bm = blockIdx.y;

    __shared__ float As[BK][68];
    __shared__ float Bs[BK][36];

    const float* Ag = A + (size_t)(bm * 64) * 5120;
    const float* Bg = B + (size_t)(bn * 32) * 5120;

    const int a_kq = (tid % 8) * 4;
    const int a_m  = tid / 8;
    const int m0 = (tid / 16) * 4;
    const int n0 = (tid % 16) * 2;

    float4 pa0 = *(const float4*)&Ag[(size_t)a_m      * 5120 + a_kq];
    float4 pa1 = *(const float4*)&Ag[(size_t)(a_m+32) * 5120 + a_kq];
    float4 pb0 = *(const float4*)&Bg[(size_t)a_m      * 5120 + a_kq];

    float acc[4][2] = {};

    for (int k0 = 0; k0 < 5120; k0 += BK) {
        #pragma unroll
        for (int j = 0; j < 4; ++j) {
            As[a_kq + j][a_m]      = ((const float*)&pa0)[j];
            As[a_kq + j][a_m + 32] = ((const float*)&pa1)[j];
            Bs[a_kq + j][a_m]      = ((const float*)&pb0)[j];
        }
        __syncthreads();
        if (k0 + BK < 5120) {
            pa0 = *(const float4*)&Ag[(size_t)a_m      * 5120 + (k0 + BK) + a_kq];
            pa1 = *(const float4*)&Ag[(size_t)(a_m+32) * 5120 + (k0 + BK) + a_kq];
            pb0 = *(const float4*)&Bg[(size_t)a_m      * 5120 + (k0 + BK) + a_kq];
        }
        #pragma unroll
        for (int k = 0; k < BK; ++k) {
            float4 av = *(const float4*)&As[k][m0];
            float2 bv = *(const float2*)&Bs[k][n0];
            const float* ap = (const float*)&av;
            const float* bp = (const float*)&bv;
            #pragma unroll
            for (int i = 0; i < 4; ++i)
                #pragma unroll
                for (int j = 0; j < 2; ++j)
                    acc[i][j] = fmaf(ap[i], bp[j], acc[i][j]);
        }
        __syncthreads();
    }

    #pragma unroll
    for (int i = 0; i < 4; ++i) {
        int row = bm * 64 + m0 + i;
        #pragma unroll
        for (int j = 0; j < 2; ++j) {
            int col = bn * 32 + n0 + j;
            out[(size_t)row * 512 + col] = fast_tanh(acc[i][j] + bias[col]);
        }
    }
}

extern "C" void kernel_launch(void* const* d_in, const int* in_sizes, int n_in,
                              void* d_out, int out_size, void* d_ws, size_t ws_size,
                              hipStream_t stream) {
    const float* x    = (const float*)d_in[0];
    const float* w1   = (const float*)d_in[1];
    const float* b1   = (const float*)d_in[2];
    const float* w2   = (const float*)d_in[3];
    const float* b2   = (const float*)d_in[4];
    const float* w3   = (const float*)d_in[5];
    const float* b3   = (const float*)d_in[6];
    const float* code = (const float*)d_in[7];
    const float* d1w  = (const float*)d_in[8];
    const float* d1b  = (const float*)d_in[9];
    const float* d2w  = (const float*)d_in[10];
    const float* d2b  = (const float*)d_in[11];
    const float* fcw  = (const float*)d_in[12];
    const float* fcb  = (const float*)d_in[13];
    float* out  = (float*)d_out;
    float* flat = (float*)d_ws;   // (1024, 5120) f32 = 20 MB

    const int Bsz = in_sizes[0] / TT;   // 1024

    enc_dec_kernel<<<Bsz, 256, 0, stream>>>(x, w1, b1, w2, b2, w3, b3, code,
                                            d1w, d1b, d2w, d2b, flat);

    dim3 grid(512 / 32, Bsz / 64);
    fc_kernel<<<grid, 256, 0, stream>>>(flat, fcw, fcb, out);
}

// Round 3
// 109.049 us; speedup vs baseline: 10.1032x; 2.2673x over previous
//
#include <hip/hip_runtime.h>
#include <hip/hip_bf16.h>

#define TT 512
#define TS 520   // LDS row stride: 4-halo | 512 | 4-halo
#define HO 4
#define NCH 10
#define K_FC 5120

typedef _Float16 h8 __attribute__((ext_vector_type(8)));
typedef float f32x16 __attribute__((ext_vector_type(16)));
typedef __attribute__((address_space(1))) const void GAS;
typedef __attribute__((address_space(3))) void LAS;

__device__ __forceinline__ float rlane(float v, int l) {
    return __uint_as_float(__builtin_amdgcn_readlane(__float_as_uint(v), l));
}
__device__ __forceinline__ float fast_tanh(float v) {
    float e = __expf(2.0f * v);
    return 1.0f - 2.0f / (e + 1.0f);
}

// ---------------------------------------------------------------------------
// fcw (512x5120 f32) -> f16
__global__ __launch_bounds__(256) void convert_w_kernel(
    const float* __restrict__ src, _Float16* __restrict__ dst)
{
    int i = blockIdx.x * 256 + threadIdx.x;   // one h8 per thread
    float4 a = ((const float4*)src)[i * 2];
    float4 b = ((const float4*)src)[i * 2 + 1];
    h8 v;
    v[0] = (_Float16)a.x; v[1] = (_Float16)a.y; v[2] = (_Float16)a.z; v[3] = (_Float16)a.w;
    v[4] = (_Float16)b.x; v[5] = (_Float16)b.y; v[6] = (_Float16)b.z; v[7] = (_Float16)b.w;
    *(h8*)&dst[(size_t)i * 8] = v;
}

// ---------------------------------------------------------------------------
// One block per batch row; weights broadcast via v_readlane. Emits f16 flat.
__global__ __launch_bounds__(256, 3) void enc_dec_kernel(
    const float* __restrict__ x,
    const float* __restrict__ w1, const float* __restrict__ b1,
    const float* __restrict__ w2, const float* __restrict__ b2,
    const float* __restrict__ w3, const float* __restrict__ b3,
    const float* __restrict__ code,
    const float* __restrict__ d1w, const float* __restrict__ d1b,
    const float* __restrict__ d2w, const float* __restrict__ d2b,
    _Float16* __restrict__ flat)
{
    __shared__ float xbuf[TS];
    __shared__ float bufA[NCH * TS];
    __shared__ float bufB[NCH * TS];

    const int tid  = threadIdx.x;
    const int lane = tid & 63;
    const int b    = blockIdx.x;
    const int t0   = tid;
    const int t1   = tid + 256;

    if (tid < 80) {
        int c = tid >> 3, j = tid & 7;
        int pos = c * TS + ((j < 4) ? j : TT + j);
        bufA[pos] = 0.f;
        bufB[pos] = 0.f;
    }
    if (tid < 8) xbuf[(tid < 4) ? tid : TT + tid] = 0.f;
    if (tid < 128)
        *(float4*)&xbuf[HO + tid * 4] = ((const float4*)(x + (size_t)b * TT))[tid];
    __syncthreads();

    // conv1: 1->5, k=3, relu
    {
        float w1r = w1[min(lane, 14)];
        float b1r = (lane < 5) ? b1[lane] : 0.f;
        float xm0 = xbuf[HO + t0 - 1], x00 = xbuf[HO + t0], xp0 = xbuf[HO + t0 + 1];
        float xm1 = xbuf[HO + t1 - 1], x01 = xbuf[HO + t1], xp1 = xbuf[HO + t1 + 1];
        #pragma unroll
        for (int o = 0; o < 5; ++o) {
            float k0 = rlane(w1r, o * 3 + 0);
            float k1 = rlane(w1r, o * 3 + 1);
            float k2 = rlane(w1r, o * 3 + 2);
            float bb = rlane(b1r, o);
            float a0 = fmaf(k0, xm0, fmaf(k1, x00, fmaf(k2, xp0, bb)));
            float a1 = fmaf(k0, xm1, fmaf(k1, x01, fmaf(k2, xp1, bb)));
            bufA[o * TS + HO + t0] = fmaxf(a0, 0.f);
            bufA[o * TS + HO + t1] = fmaxf(a1, 0.f);
        }
    }
    __syncthreads();

    // conv2: 5->10, k=5, relu
    {
        float wr[4];
        #pragma unroll
        for (int r = 0; r < 4; ++r) wr[r] = w2[min(r * 64 + lane, 249)];
        float br = (lane < 10) ? b2[lane] : 0.f;
        float a0[10], a1[10];
        #pragma unroll
        for (int o = 0; o < 10; ++o) { float bb = rlane(br, o); a0[o] = bb; a1[o] = bb; }
        #pragma unroll
        for (int i = 0; i < 5; ++i) {
            #pragma unroll
            for (int j = 0; j < 5; ++j) {
                float ta = bufA[i * TS + HO + t0 - 2 + j];
                float tb = bufA[i * TS + HO + t1 - 2 + j];
                #pragma unroll
                for (int o = 0; o < 10; ++o) {
                    const int e = (o * 5 + i) * 5 + j;
                    float wv = rlane(wr[e >> 6], e & 63);
                    a0[o] = fmaf(wv, ta, a0[o]);
                    a1[o] = fmaf(wv, tb, a1[o]);
                }
            }
        }
        #pragma unroll
        for (int o = 0; o < 10; ++o) {
            bufB[o * TS + HO + t0] = fmaxf(a0[o], 0.f);
            bufB[o * TS + HO + t1] = fmaxf(a1[o], 0.f);
        }
    }
    __syncthreads();

    // conv3: 10->10, k=7, tanh
    {
        float wr[11];
        #pragma unroll
        for (int r = 0; r < 11; ++r) wr[r] = w3[min(r * 64 + lane, 699)];
        float br = (lane < 10) ? b3[lane] : 0.f;
        float a0[10], a1[10];
        #pragma unroll
        for (int o = 0; o < 10; ++o) { float bb = rlane(br, o); a0[o] = bb; a1[o] = bb; }
        #pragma unroll
        for (int i = 0; i < 10; ++i) {
            #pragma unroll
            for (int j = 0; j < 7; ++j) {
                float ta = bufB[i * TS + HO + t0 - 3 + j];
                float tb = bufB[i * TS + HO + t1 - 3 + j];
                #pragma unroll
                for (int o = 0; o < 10; ++o) {
                    const int e = (o * 10 + i) * 7 + j;
                    float wv = rlane(wr[e >> 6], e & 63);
                    a0[o] = fmaf(wv, ta, a0[o]);
                    a1[o] = fmaf(wv, tb, a1[o]);
                }
            }
        }
        #pragma unroll
        for (int o = 0; o < 10; ++o) {
            bufA[o * TS + HO + t0] = fast_tanh(a0[o]);
            bufA[o * TS + HO + t1] = fast_tanh(a1[o]);
        }
    }
    __syncthreads();

    // VQ: softmax(2*cross - c2), no max pass (|arg| small)
    {
        float cr5[5];
        #pragma unroll
        for (int r = 0; r < 5; ++r) cr5[r] = code[min(r * 64 + lane, 319)];
        float hv0[10], hv1[10];
        #pragma unroll
        for (int c = 0; c < 10; ++c) {
            hv0[c] = bufA[c * TS + HO + t0];
            hv1[c] = bufA[c * TS + HO + t1];
        }
        float qv0[10] = {}, qv1[10] = {};
        float sum0 = 0.f, sum1 = 0.f;
        #pragma unroll
        for (int k = 0; k < 32; ++k) {
            float cvv[10];
            float c0 = 0.f, c1 = 0.f, cc = 0.f;
            #pragma unroll
            for (int c = 0; c < 10; ++c) {
                const int e = c * 32 + k;
                float cv = rlane(cr5[e >> 6], e & 63);
                cvv[c] = cv;
                c0 = fmaf(cv, hv0[c], c0);
                c1 = fmaf(cv, hv1[c], c1);
                cc = fmaf(cv, cv, cc);
            }
            float e0 = __expf(fmaf(2.f, c0, -cc));
            float e1 = __expf(fmaf(2.f, c1, -cc));
            sum0 += e0;
            sum1 += e1;
            #pragma unroll
            for (int c = 0; c < 10; ++c) {
                qv0[c] = fmaf(e0, cvv[c], qv0[c]);
                qv1[c] = fmaf(e1, cvv[c], qv1[c]);
            }
        }
        float inv0 = 1.0f / sum0, inv1 = 1.0f / sum1;
        #pragma unroll
        for (int c = 0; c < 10; ++c) {
            bufB[c * TS + HO + t0] = qv0[c] * inv0;
            bufB[c * TS + HO + t1] = qv1[c] * inv1;
        }
    }
    __syncthreads();

    // d1: 10->10, k=5, relu
    {
        float wr[8];
        #pragma unroll
        for (int r = 0; r < 8; ++r) wr[r] = d1w[min(r * 64 + lane, 499)];
        float br = (lane < 10) ? d1b[lane] : 0.f;
        float a0[10], a1[10];
        #pragma unroll
        for (int o = 0; o < 10; ++o) { float bb = rlane(br, o); a0[o] = bb; a1[o] = bb; }
        #pragma unroll
        for (int i = 0; i < 10; ++i) {
            #pragma unroll
            for (int j = 0; j < 5; ++j) {
                float ta = bufB[i * TS + HO + t0 - 2 + j];
                float tb = bufB[i * TS + HO + t1 - 2 + j];
                #pragma unroll
                for (int o = 0; o < 10; ++o) {
                    const int e = (o * 10 + i) * 5 + j;
                    float wv = rlane(wr[e >> 6], e & 63);
                    a0[o] = fmaf(wv, ta, a0[o]);
                    a1[o] = fmaf(wv, tb, a1[o]);
                }
            }
        }
        #pragma unroll
        for (int o = 0; o < 10; ++o) {
            bufA[o * TS + HO + t0] = fmaxf(a0[o], 0.f);
            bufA[o * TS + HO + t1] = fmaxf(a1[o], 0.f);
        }
    }
    __syncthreads();

    // d2: 10->10, k=5, relu
    {
        float wr[8];
        #pragma unroll
        for (int r = 0; r < 8; ++r) wr[r] = d2w[min(r * 64 + lane, 499)];
        float br = (lane < 10) ? d2b[lane] : 0.f;
        float a0[10], a1[10];
        #pragma unroll
        for (int o = 0; o < 10; ++o) { float bb = rlane(br, o); a0[o] = bb; a1[o] = bb; }
        #pragma unroll
        for (int i = 0; i < 10; ++i) {
            #pragma unroll
            for (int j = 0; j < 5; ++j) {
                float ta = bufA[i * TS + HO + t0 - 2 + j];
                float tb = bufA[i * TS + HO + t1 - 2 + j];
                #pragma unroll
                for (int o = 0; o < 10; ++o) {
                    const int e = (o * 10 + i) * 5 + j;
                    float wv = rlane(wr[e >> 6], e & 63);
                    a0[o] = fmaf(wv, ta, a0[o]);
                    a1[o] = fmaf(wv, tb, a1[o]);
                }
            }
        }
        #pragma unroll
        for (int o = 0; o < 10; ++o) {
            bufB[o * TS + HO + t0] = fmaxf(a0[o], 0.f);
            bufB[o * TS + HO + t1] = fmaxf(a1[o], 0.f);
        }
    }
    __syncthreads();

    // flat row -> f16, 16B stores
    {
        _Float16* dst = flat + (size_t)b * (NCH * TT);
        for (int i = tid; i < 640; i += 256) {         // 640 h8-groups
            int c  = i >> 6;
            int t8 = (i & 63) << 3;
            float4 v0 = *(const float4*)&bufB[c * TS + HO + t8];
            float4 v1 = *(const float4*)&bufB[c * TS + HO + t8 + 4];
            h8 hv;
            hv[0] = (_Float16)v0.x; hv[1] = (_Float16)v0.y;
            hv[2] = (_Float16)v0.z; hv[3] = (_Float16)v0.w;
            hv[4] = (_Float16)v1.x; hv[5] = (_Float16)v1.y;
            hv[6] = (_Float16)v1.z; hv[7] = (_Float16)v1.w;
            *(h8*)&dst[c * TT + t8] = hv;
        }
    }
}

// ---------------------------------------------------------------------------
// FC via f16 MFMA. BM=BN=64, grid (16 m)x(8 n)=128 blocks, 4 waves.
// Each wave computes the full 64x64 tile over a K-quarter (chunks w*4..w*4+3
// of each staged BK=128 tile); cross-wave sum + bias + tanh in LDS epilogue.
// LDS tiles [64 rows][128 k f16] = 256B rows = 16 chunks of 16B, XOR-swizzled
// (chunk ^ (row&7)) via pre-swizzled global source + swizzled ds_read (both
// sides, rule 21). Double-buffered: 2*(16K+16K) = 64 KB.
__global__ __launch_bounds__(256, 1) void fc_mfma_kernel(
    const _Float16* __restrict__ A,    // flat (1024, 5120)
    const _Float16* __restrict__ W,    // fcw_h (512, 5120)
    const float* __restrict__ bias,    // (512)
    float* __restrict__ out)           // (1024, 512)
{
    __shared__ __align__(16) unsigned char smem[65536];

    const int tid  = threadIdx.x;
    const int lane = tid & 63;
    const int w    = tid >> 6;

    // XCD-aware swizzle: 128 wgs, 8 XCDs -> contiguous 16-wg chunks per XCD
    const int bid = blockIdx.x;
    const int swz = (bid & 7) * 16 + (bid >> 3);
    const int m0 = (swz >> 3) * 64;   // 16 m-tiles
    const int n0 = (swz & 7) * 64;    // 8 n-tiles

    const int l31 = lane & 31;
    const int lh  = lane >> 5;        // 0/1 : k-half within kstep16
    const int rl16 = lane >> 4;       // staging row within quad
    const int c_lds = lane & 15;      // staging chunk

    f32x16 acc00 = {}, acc01 = {}, acc10 = {}, acc11 = {};

    const _Float16* Asrc = A + (size_t)m0 * K_FC;
    const _Float16* Wsrc = W + (size_t)n0 * K_FC;

    // ---- staging helper: superstep s into buffer buf ----
    auto stage = [&](int buf, int s) {
        unsigned char* Ad = smem + buf * 32768;
        unsigned char* Bd = Ad + 16384;
        const int k0 = s * 128;
        #pragma unroll
        for (int j = 0; j < 4; ++j) {
            const int i = w * 4 + j;              // issue 0..15
            const int rloc = 4 * i + rl16;        // row 0..63
            const int csrc = c_lds ^ (rloc & 7);  // pre-swizzled source chunk
            __builtin_amdgcn_global_load_lds(
                (GAS*)(Asrc + (size_t)rloc * K_FC + k0 + csrc * 8),
                (LAS*)(Ad + i * 1024), 16, 0, 0);
        }
        #pragma unroll
        for (int j = 0; j < 4; ++j) {
            const int i = w * 4 + j;
            const int rloc = 4 * i + rl16;
            const int csrc = c_lds ^ (rloc & 7);
            __builtin_amdgcn_global_load_lds(
                (GAS*)(Wsrc + (size_t)rloc * K_FC + k0 + csrc * 8),
                (LAS*)(Bd + i * 1024), 16, 0, 0);
        }
    };

    stage(0, 0);
    __syncthreads();

    for (int s = 0; s < 40; ++s) {
        const int cur = s & 1;
        if (s + 1 < 40) stage(cur ^ 1, s + 1);

        const unsigned char* Ab = smem + cur * 32768;
        const unsigned char* Bb = Ab + 16384;
        #pragma unroll
        for (int ks = 0; ks < 2; ++ks) {
            const int chunk = w * 4 + ks * 2 + lh;         // wave's k-chunk
            const int swzo  = ((chunk ^ (lane & 7)) << 4); // read swizzle
            h8 af0 = *(const h8*)(Ab +        l31 * 256 + swzo);
            h8 af1 = *(const h8*)(Ab + 8192 + l31 * 256 + swzo);
            h8 bf0 = *(const h8*)(Bb +        l31 * 256 + swzo);
            h8 bf1 = *(const h8*)(Bb + 8192 + l31 * 256 + swzo);
            acc00 = __builtin_amdgcn_mfma_f32_32x32x16_f16(af0, bf0, acc00, 0, 0, 0);
            acc01 = __builtin_amdgcn_mfma_f32_32x32x16_f16(af0, bf1, acc01, 0, 0, 0);
            acc10 = __builtin_amdgcn_mfma_f32_32x32x16_f16(af1, bf0, acc10, 0, 0, 0);
            acc11 = __builtin_amdgcn_mfma_f32_32x32x16_f16(af1, bf1, acc11, 0, 0, 0);
        }
        __syncthreads();
    }

    // ---- cross-wave reduce + bias + tanh ----
    // layout: [w][frag f][rq][lane][rr]  f32; 4 * 16 KB
    float* red = (float*)smem;
    {
        float* base = red + w * 4096;
        #pragma unroll
        for (int rq = 0; rq < 4; ++rq) {
            float4 v;
            v.x = acc00[rq*4+0]; v.y = acc00[rq*4+1]; v.z = acc00[rq*4+2]; v.w = acc00[rq*4+3];
            *(float4*)&base[0 * 1024 + rq * 256 + lane * 4] = v;
            v.x = acc01[rq*4+0]; v.y = acc01[rq*4+1]; v.z = acc01[rq*4+2]; v.w = acc01[rq*4+3];
            *(float4*)&base[1 * 1024 + rq * 256 + lane * 4] = v;
            v.x = acc10[rq*4+0]; v.y = acc10[rq*4+1]; v.z = acc10[rq*4+2]; v.w = acc10[rq*4+3];
            *(float4*)&base[2 * 1024 + rq * 256 + lane * 4] = v;
            v.x = acc11[rq*4+0]; v.y = acc11[rq*4+1]; v.z = acc11[rq*4+2]; v.w = acc11[rq*4+3];
            *(float4*)&base[3 * 1024 + rq * 256 + lane * 4] = v;
        }
    }
    __syncthreads();
    {
        const int f  = tid >> 6;          // 0..3 : frag = mf*2+nf
        const int lo = tid & 63;          // original lane
        const int mf = f >> 1, nf = f & 1;
        const int n  = nf * 32 + (lo & 31);
        const float bv = bias[n0 + n];
        #pragma unroll
        for (int rq = 0; rq < 4; ++rq) {
            const int idx = f * 1024 + rq * 256 + lo * 4;
            float4 s0 = *(const float4*)&red[idx];
            float4 s1 = *(const float4*)&red[4096 + idx];
            float4 s2 = *(const float4*)&red[8192 + idx];
            float4 s3 = *(const float4*)&red[12288 + idx];
            #pragma unroll
            for (int rr = 0; rr < 4; ++rr) {
                float sum = ((const float*)&s0)[rr] + ((const float*)&s1)[rr]
                          + ((const float*)&s2)[rr] + ((const float*)&s3)[rr];
                const int m = mf * 32 + rr + 8 * rq + 4 * (lo >> 5);
                out[(size_t)(m0 + m) * 512 + n0 + n] = fast_tanh(sum + bv);
            }
        }
    }
}

extern "C" void kernel_launch(void* const* d_in, const int* in_sizes, int n_in,
                              void* d_out, int out_size, void* d_ws, size_t ws_size,
                              hipStream_t stream) {
    const float* x    = (const float*)d_in[0];
    const float* w1   = (const float*)d_in[1];
    const float* b1   = (const float*)d_in[2];
    const float* w2   = (const float*)d_in[3];
    const float* b2   = (const float*)d_in[4];
    const float* w3   = (const float*)d_in[5];
    const float* b3   = (const float*)d_in[6];
    const float* code = (const float*)d_in[7];
    const float* d1w  = (const float*)d_in[8];
    const float* d1b  = (const float*)d_in[9];
    const float* d2w  = (const float*)d_in[10];
    const float* d2b  = (const float*)d_in[11];
    const float* fcw  = (const float*)d_in[12];
    const float* fcb  = (const float*)d_in[13];
    float* out = (float*)d_out;

    _Float16* flat_h = (_Float16*)d_ws;                          // 10.0 MB
    _Float16* fcw_h  = (_Float16*)((char*)d_ws + 10485760);      //  5.0 MB

    const int Bsz = in_sizes[0] / TT;   // 1024

    convert_w_kernel<<<1280, 256, 0, stream>>>(fcw, fcw_h);
    enc_dec_kernel<<<Bsz, 256, 0, stream>>>(x, w1, b1, w2, b2, w3, b3, code,
                                            d1w, d1b, d2w, d2b, flat_h);
    fc_mfma_kernel<<<128, 256, 0, stream>>>(flat_h, fcw_h, fcb, out);
}